// Round 5
// baseline (657.946 us; speedup 1.0000x reference)
//
#include <hip/hip_runtime.h>
#include <cstddef>

// SkipGRU on MI355X (gfx950) — round 10.
// Rounds 8/9 falsified LDS-BW and barrier-rate theories (both ~neutral/worse).
// Structural fix instead: x@W does NOT depend on h -> hoist ALL 16 steps'
// phase-0 into ONE batched GEMM (xw_gemm: M=65536,N=1536,K=512, 8192 blocks,
// round-7-proven 64nx192c tile + counted-vmcnt pipeline). Results (gate
// pre-activations, f32) stored to xp in a per-block per-thread fragment
// layout (coalesced 16B/lane on both write and read). gru_step keeps ONLY
// the recurrent h@U half (16 K-chunks, exact round-7 counted pipeline) and
// adds xp fragments in the epilogue. Sequential critical path halves.
// xw_gemm XCD mapping: per XCD, 8 consecutive (t,nb) x all 8 hb resident ->
// L2 set = Bt 3MB + 8 A-tiles (512KB) < 4MB.
//
// Layouts:
//  xb[t][nb(64)][kt(16)][g(4)][row(64)][8] bf16 granules (16B).
//  Bt[cc(24)][kt(32)][g(4)][col(64)][8]    (cc = 64 gemm-cols).
//  h ping-pong: same granule layout as xb per nb.
//  xp[bp(8192)][j(12)][tid(256)] floatx4; bp=(t*64+nb)*8+hb, j=gate*4+mi*2+ci.

typedef unsigned short u16;
typedef __attribute__((ext_vector_type(8))) short short8;
typedef __attribute__((ext_vector_type(8))) u16 u16x8;
typedef __attribute__((ext_vector_type(4))) float floatx4;

#define MFMA16(a, b, c) __builtin_amdgcn_mfma_f32_16x16x32_bf16((a), (b), (c), 0, 0, 0)

__device__ __forceinline__ u16 f32_to_bf16(float f) {
  union { float f; unsigned int u; } c; c.f = f;
  unsigned int u = c.u + 0x7FFFu + ((c.u >> 16) & 1u);  // RNE
  return (u16)(u >> 16);
}
__device__ __forceinline__ float bf16_to_f32(u16 v) {
  union { unsigned int u; float f; } c; c.u = ((unsigned int)v) << 16;
  return c.f;
}
__device__ __forceinline__ float sigmoidf_(float x) {
  return 1.0f / (1.0f + __expf(-x));
}
__device__ __forceinline__ void gload_lds16(const void* g, void* l) {
  __builtin_amdgcn_global_load_lds(
      (const __attribute__((address_space(1))) unsigned int*)g,
      (__attribute__((address_space(3))) unsigned int*)l, 16, 0, 0);
}

// ---------------------------------------------------------------------------
// pack_x: coalesced. Block = one (t, nb): 64 rows x 512 c. (unchanged)
// ---------------------------------------------------------------------------
__global__ __launch_bounds__(256)
void pack_x(const float* __restrict__ x, u16* __restrict__ xb) {
  __shared__ u16 sm[64 * 512];              // 64KB
  const int t = blockIdx.x >> 6;
  const int nb = blockIdx.x & 63;
  const int tid = threadIdx.x;
#pragma unroll
  for (int it = 0; it < 16; ++it) {
    int idx = it * 256 + tid;
    int row = idx >> 6, ch = idx & 63;      // row 0..63, ch = 8-float chunk
    int xrow = (nb * 2 + (row >> 5)) * 512 + t * 32 + (row & 31);
    const float* src = x + (size_t)xrow * 512 + ch * 8;
    floatx4 va = *(const floatx4*)src;
    floatx4 vb = *(const floatx4*)(src + 4);
    u16x8 pk;
    pk[0] = f32_to_bf16(va[0]); pk[1] = f32_to_bf16(va[1]);
    pk[2] = f32_to_bf16(va[2]); pk[3] = f32_to_bf16(va[3]);
    pk[4] = f32_to_bf16(vb[0]); pk[5] = f32_to_bf16(vb[1]);
    pk[6] = f32_to_bf16(vb[2]); pk[7] = f32_to_bf16(vb[3]);
    *(u16x8*)&sm[row * 512 + (ch ^ (row & 7)) * 8] = pk;
  }
  __syncthreads();
  u16* dst = xb + (size_t)blockIdx.x * 32768;   // blockIdx = t*64+nb = layout order
#pragma unroll
  for (int it = 0; it < 16; ++it) {
    int idx = it * 256 + tid;
    int row = idx & 63, g = (idx >> 6) & 3, kt = idx >> 8;
    int ch = kt * 4 + g;
    u16x8 vv = *(const u16x8*)&sm[row * 512 + (ch ^ (row & 7)) * 8];
    *(u16x8*)(dst + (size_t)idx * 8) = vv;
  }
}

// ---------------------------------------------------------------------------
// pack_Bt: [W;U] -> Bt bf16 [cc(24)][kt(32)][g(4)][col(64)][8] (unchanged)
// ---------------------------------------------------------------------------
__global__ void pack_Bt(const float* __restrict__ W, const float* __restrict__ U,
                        u16* __restrict__ Bt) {
  size_t gid = (size_t)blockIdx.x * 256 + threadIdx.x;   // < 196608
  int col = (int)(gid & 63);
  int g   = (int)((gid >> 6) & 3);
  int kt  = (int)((gid >> 8) & 31);
  int cc  = (int)(gid >> 13);
  int c = cc * 64 + col;
  int k0 = kt * 32 + g * 8;
  u16x8 pk;
#pragma unroll
  for (int j = 0; j < 8; ++j) {
    int k = k0 + j;
    float v = (k < 512) ? W[(size_t)k * 1536 + c] : U[(size_t)(k - 512) * 1536 + c];
    pk[j] = f32_to_bf16(v);
  }
  *(u16x8*)(Bt + gid * 8) = pk;
}

// ---------------------------------------------------------------------------
// xw_gemm: batched x@W for ALL 16 timesteps. Grid 8192, 256 thr, 4 waves.
// Block = (t, nb, hb): 64 rows x 192 cols (3 gates x 64), 16 K-chunks.
// XCD mapping: x=idx&7, g=idx>>3 -> hb=g&7, tn=(g>>3)*8+x. Per XCD: all hb
// (full Bt hot in L2) x 8-consecutive-tn A tiles.
// ---------------------------------------------------------------------------
__global__ __launch_bounds__(256)
void xw_gemm(const u16* __restrict__ xb, const u16* __restrict__ Bt,
             float* __restrict__ xp) {
  __shared__ alignas(16) char sm[65536];    // 4 x 16KB ring -> 2 blocks/CU
  const int tid = threadIdx.x;
  const int xcd = blockIdx.x & 7;
  const int g8  = blockIdx.x >> 3;
  const int hb  = g8 & 7;
  const int tn  = (g8 >> 3) * 8 + xcd;      // 0..1023 = t*64+nb
  const int w = __builtin_amdgcn_readfirstlane(tid >> 6);
  const int lane = tid & 63;
  const int wy = w >> 1, wx = w & 1;
  const int q = lane >> 4, lc = lane & 15;

  const u16* aB = xb + (size_t)tn * 32768;
  const int cs0 = hb, cs1 = 8 + hb, cs2 = 16 + hb;

  floatx4 acZ[2][2] = {{{0.f,0.f,0.f,0.f},{0.f,0.f,0.f,0.f}},{{0.f,0.f,0.f,0.f},{0.f,0.f,0.f,0.f}}};
  floatx4 acR[2][2] = {{{0.f,0.f,0.f,0.f},{0.f,0.f,0.f,0.f}},{{0.f,0.f,0.f,0.f},{0.f,0.f,0.f,0.f}}};
  floatx4 acX[2][2] = {{{0.f,0.f,0.f,0.f},{0.f,0.f,0.f,0.f}},{{0.f,0.f,0.f,0.f},{0.f,0.f,0.f,0.f}}};

  const int wo = w * 1024;

  auto stage = [&](int kt, int bsel) {
    char* lds = sm + bsel * 16384;
    gload_lds16((const char*)(aB + (size_t)kt * 2048) + wo + lane * 16, lds + wo);
    gload_lds16((const char*)(Bt + (size_t)(cs0 * 32 + kt) * 2048) + wo + lane * 16,
                lds + 4096 + wo);
    gload_lds16((const char*)(Bt + (size_t)(cs1 * 32 + kt) * 2048) + wo + lane * 16,
                lds + 8192 + wo);
    gload_lds16((const char*)(Bt + (size_t)(cs2 * 32 + kt) * 2048) + wo + lane * 16,
                lds + 12288 + wo);
  };

  auto compute = [&](int slot) {
    const char* lds = sm + slot * 16384;
    short8 a0 = *(const short8*)(lds + (q * 64 + wy * 32 + lc) * 16);
    short8 a1 = *(const short8*)(lds + (q * 64 + wy * 32 + 16 + lc) * 16);
#pragma unroll
    for (int ci = 0; ci < 2; ++ci) {
      int co = (q * 64 + wx * 32 + ci * 16 + lc) * 16;
      short8 bz = *(const short8*)(lds + 4096 + co);
      short8 br = *(const short8*)(lds + 8192 + co);
      short8 bh = *(const short8*)(lds + 12288 + co);
      acZ[0][ci] = MFMA16(a0, bz, acZ[0][ci]);
      acZ[1][ci] = MFMA16(a1, bz, acZ[1][ci]);
      acR[0][ci] = MFMA16(a0, br, acR[0][ci]);
      acR[1][ci] = MFMA16(a1, br, acR[1][ci]);
      acX[0][ci] = MFMA16(a0, bh, acX[0][ci]);
      acX[1][ci] = MFMA16(a1, bh, acX[1][ci]);
    }
  };

  // Counted pipeline, 3 ahead (round-7 pattern, 16 chunks).
  stage(0, 0); stage(1, 1); stage(2, 2);
  for (int kt = 0; kt < 14; ++kt) {
    asm volatile("s_waitcnt vmcnt(8)" ::: "memory");
    __builtin_amdgcn_s_barrier();
    if (kt < 13) stage(kt + 3, (kt + 3) & 3);
    __builtin_amdgcn_s_setprio(1);
    compute(kt & 3);
    __builtin_amdgcn_s_setprio(0);
  }
  asm volatile("s_waitcnt vmcnt(4)" ::: "memory");
  __builtin_amdgcn_s_barrier();
  __builtin_amdgcn_s_setprio(1);
  compute(2);                                // kt=14
  __builtin_amdgcn_s_setprio(0);
  asm volatile("s_waitcnt vmcnt(0)" ::: "memory");
  __builtin_amdgcn_s_barrier();
  __builtin_amdgcn_s_setprio(1);
  compute(3);                                // kt=15
  __builtin_amdgcn_s_setprio(0);

  // Write fragments: xp[bp][j][tid] floatx4, j = gate*4 + mi*2 + ci.
  const size_t bp = (size_t)tn * 8 + hb;
  float* base = xp + (bp * 12) * 1024;       // 12 j-slots x 256 tid x 4 f32
#pragma unroll
  for (int mi = 0; mi < 2; ++mi)
#pragma unroll
    for (int ci = 0; ci < 2; ++ci) {
      int j = mi * 2 + ci;
      *(floatx4*)(base + (size_t)(0 * 4 + j) * 1024 + tid * 4) = acZ[mi][ci];
      *(floatx4*)(base + (size_t)(1 * 4 + j) * 1024 + tid * 4) = acR[mi][ci];
      *(floatx4*)(base + (size_t)(2 * 4 + j) * 1024 + tid * 4) = acX[mi][ci];
    }
}

// ---------------------------------------------------------------------------
// gru_step: one GRU timestep — h@U ONLY (16 K-chunks) + xp add in epilogue.
// Grid 512 linear, XCD-swizzled: nb = (idx>>6)*8 + (idx&7), hb = (idx>>3)&7.
// Block tile 64n x 192c; 4 waves; LDS 4 x 16KB ring; round-7 counted pipeline.
// ---------------------------------------------------------------------------
__global__ __launch_bounds__(256)
void gru_step(const u16* __restrict__ Bt, const float* __restrict__ bias,
              const float* __restrict__ xp,
              const u16* __restrict__ h_in, u16* __restrict__ h_out,
              float* __restrict__ out, int t, int first, int last) {
  __shared__ alignas(16) char sm[65536];    // 4 x 16KB ring -> 2 blocks/CU
  const int tid = threadIdx.x;
  const int idx = blockIdx.x;
  const int nb = ((idx >> 6) << 3) | (idx & 7);   // 0..63
  const int hb = (idx >> 3) & 7;                  // 0..7
  const int w = __builtin_amdgcn_readfirstlane(tid >> 6);
  const int lane = tid & 63;
  const int wy = w >> 1, wx = w & 1;
  const int q = lane >> 4, lc = lane & 15;

  const u16* htB = h_in + (size_t)nb * 32768;
  const int cs0 = hb, cs1 = 8 + hb, cs2 = 16 + hb;

  floatx4 acZ[2][2] = {{{0.f,0.f,0.f,0.f},{0.f,0.f,0.f,0.f}},{{0.f,0.f,0.f,0.f},{0.f,0.f,0.f,0.f}}};
  floatx4 acR[2][2] = {{{0.f,0.f,0.f,0.f},{0.f,0.f,0.f,0.f}},{{0.f,0.f,0.f,0.f},{0.f,0.f,0.f,0.f}}};
  floatx4 acH[2][2] = {{{0.f,0.f,0.f,0.f},{0.f,0.f,0.f,0.f}},{{0.f,0.f,0.f,0.f},{0.f,0.f,0.f,0.f}}};

  const int wo = w * 1024;

  auto stage = [&](int kt, int bsel) {      // kt = 0..15 over h chunks
    char* lds = sm + bsel * 16384;
    gload_lds16((const char*)(htB + (size_t)kt * 2048) + wo + lane * 16, lds + wo);
    gload_lds16((const char*)(Bt + (size_t)(cs0 * 32 + 16 + kt) * 2048) + wo + lane * 16,
                lds + 4096 + wo);
    gload_lds16((const char*)(Bt + (size_t)(cs1 * 32 + 16 + kt) * 2048) + wo + lane * 16,
                lds + 8192 + wo);
    gload_lds16((const char*)(Bt + (size_t)(cs2 * 32 + 16 + kt) * 2048) + wo + lane * 16,
                lds + 12288 + wo);
  };

  auto compute = [&](int slot) {
    const char* lds = sm + slot * 16384;
    short8 a0 = *(const short8*)(lds + (q * 64 + wy * 32 + lc) * 16);
    short8 a1 = *(const short8*)(lds + (q * 64 + wy * 32 + 16 + lc) * 16);
#pragma unroll
    for (int ci = 0; ci < 2; ++ci) {
      int co = (q * 64 + wx * 32 + ci * 16 + lc) * 16;
      short8 bz = *(const short8*)(lds + 4096 + co);
      short8 br = *(const short8*)(lds + 8192 + co);
      short8 bh = *(const short8*)(lds + 12288 + co);
      acZ[0][ci] = MFMA16(a0, bz, acZ[0][ci]);
      acZ[1][ci] = MFMA16(a1, bz, acZ[1][ci]);
      acR[0][ci] = MFMA16(a0, br, acR[0][ci]);
      acR[1][ci] = MFMA16(a1, br, acR[1][ci]);
      acH[0][ci] = MFMA16(a0, bh, acH[0][ci]);
      acH[1][ci] = MFMA16(a1, bh, acH[1][ci]);
    }
  };

  if (!first) {
    // Counted pipeline, 3 ahead, 16 chunks (round-7 pattern).
    stage(0, 0); stage(1, 1); stage(2, 2);
    for (int kt = 0; kt < 14; ++kt) {
      asm volatile("s_waitcnt vmcnt(8)" ::: "memory");
      __builtin_amdgcn_s_barrier();
      if (kt < 13) stage(kt + 3, (kt + 3) & 3);
      __builtin_amdgcn_s_setprio(1);
      compute(kt & 3);
      __builtin_amdgcn_s_setprio(0);
    }
    asm volatile("s_waitcnt vmcnt(4)" ::: "memory");
    __builtin_amdgcn_s_barrier();
    __builtin_amdgcn_s_setprio(1);
    compute(2);                              // kt=14
    __builtin_amdgcn_s_setprio(0);
    asm volatile("s_waitcnt vmcnt(0)" ::: "memory");
    __builtin_amdgcn_s_barrier();
    __builtin_amdgcn_s_setprio(1);
    compute(3);                              // kt=15
    __builtin_amdgcn_s_setprio(0);
  }

  // ---- Epilogue: add xp fragments + gate math. C/D: col=lane&15, row=q*4+reg.
  __syncthreads();                           // compute done before Ct reuse
  const size_t bp = ((size_t)(t * 64 + nb)) * 8 + hb;
  const float* xbase = xp + (bp * 12) * 1024;
  floatx4 xpZ[2][2], xpR[2][2], xpX[2][2];
#pragma unroll
  for (int mi = 0; mi < 2; ++mi)
#pragma unroll
    for (int ci = 0; ci < 2; ++ci) {
      int j = mi * 2 + ci;
      xpZ[mi][ci] = *(const floatx4*)(xbase + (size_t)(0 * 4 + j) * 1024 + tid * 4);
      xpR[mi][ci] = *(const floatx4*)(xbase + (size_t)(1 * 4 + j) * 1024 + tid * 4);
      xpX[mi][ci] = *(const floatx4*)(xbase + (size_t)(2 * 4 + j) * 1024 + tid * 4);
    }
  const float* b0 = bias;
  const float* b1 = bias + 1536;
  u16* Ct = (u16*)sm;    // 64 rows x 72 u16 (9KB)
#pragma unroll
  for (int ci = 0; ci < 2; ++ci) {
    const int hcl = wx * 32 + ci * 16 + lc;    // 0..63
    const int hg = hb * 64 + hcl;              // 0..511
    const float bz = b0[hg] + b1[hg];
    const float br = b0[512 + hg] + b1[512 + hg];
    const float b0h = b0[1024 + hg];
    const float b1h = b1[1024 + hg];
    const int ktg = hg >> 5;
    const int gg = (hg >> 3) & 3;
    const size_t hbase = (((size_t)nb * 16 + ktg) * 4 + gg) * 64;
#pragma unroll
    for (int mi = 0; mi < 2; ++mi) {
#pragma unroll
      for (int reg = 0; reg < 4; ++reg) {
        const int nl = wy * 32 + mi * 16 + q * 4 + reg;   // 0..63
        const int n = nb * 64 + nl;
        float z = sigmoidf_(xpZ[mi][ci][reg] + acZ[mi][ci][reg] + bz);
        float r = sigmoidf_(xpR[mi][ci][reg] + acR[mi][ci][reg] + br);
        float hh = xpX[mi][ci][reg] + b0h + r * (acH[mi][ci][reg] + b1h);
        hh = fmaxf(hh, 0.0f);
        float hp = 0.0f;
        if (!first) hp = bf16_to_f32(h_in[(hbase + nl) * 8 + (hg & 7)]);
        float v = z * hp + (1.0f - z) * hh;
        if (last) out[(size_t)n * 512 + hg] = v;
        else      Ct[nl * 72 + hcl] = f32_to_bf16(v);
      }
    }
  }
  if (!last) {
    __syncthreads();
    // Re-emit h in granule layout: 512 granules (row64 x g4 x ktl2), 2/thread.
#pragma unroll
    for (int i = 0; i < 2; ++i) {
      int e = i * 256 + tid;
      int row = e & 63;
      int g = (e >> 6) & 3;
      int ktl = e >> 8;                         // 0..1
      u16x8 vv = *(const u16x8*)(Ct + row * 72 + ktl * 32 + g * 8);
      *(u16x8*)(h_out + ((((size_t)nb * 16 + (hb * 2 + ktl)) * 4 + g) * 64 + row) * 8) = vv;
    }
  }
}

// ---------------------------------------------------------------------------
extern "C" void kernel_launch(void* const* d_in, const int* in_sizes, int n_in,
                              void* d_out, int out_size, void* d_ws, size_t ws_size,
                              hipStream_t stream) {
  const float* x = (const float*)d_in[0];    // (128,512,512)
  const float* W = (const float*)d_in[1];    // (512,1536)
  const float* U = (const float*)d_in[2];    // (512,1536)
  const float* bias = (const float*)d_in[3]; // (2,1536)
  float* out = (float*)d_out;                // (128,16384)

  u16* xb = (u16*)d_ws;                      // 64 MiB
  u16* Bt = xb + (size_t)16 * 64 * 32768;    // 3 MiB
  u16* h0 = Bt + (size_t)1536 * 1024;        // 4 MiB
  u16* h1 = h0 + (size_t)4096 * 512;         // 4 MiB
  float* xp = (float*)(h1 + (size_t)4096 * 512);  // 384 MiB (total 459 <= 512)

  pack_x<<<1024, 256, 0, stream>>>(x, xb);
  pack_Bt<<<768, 256, 0, stream>>>(W, U, Bt);
  xw_gemm<<<8192, 256, 0, stream>>>(xb, Bt, xp);

  for (int t = 0; t < 16; ++t) {
    const u16* hin = (t & 1) ? h1 : h0;      // t=0 never reads h
    u16* hout = (t & 1) ? h0 : h1;
    gru_step<<<512, 256, 0, stream>>>(
        Bt, bias, xp, hin, hout, out, t, (t == 0) ? 1 : 0, (t == 15) ? 1 : 0);
  }
}